// Round 15
// baseline (485.846 us; speedup 1.0000x reference)
//
#include <hip/hip_runtime.h>
#include <hip/hip_bf16.h>

// QuantizedLinear: out[M,N] = inp[M,K] @ (qw[N,K] * scale[N])^T
// M = 4096, K = 4096, N = 12288.
// Round 15: BIG-WAVE-TILE i8 GEMM (fragment-BW fix).
//   Pass 1a: per-row absmax-quantize A fp32 -> int8 linear [M][K] (+ Ra[m]).
//   Pass 1b: W int32 -> int8 linear [N][K] (exact).
//   Pass 2:  256x256 block, 4 waves (2x2), 128x128 per wave, acc 8x8 frags.
//            Operand demand 32KB/wave vs 2611 MFMA-cyc -> MFMA-limited even
//            serialized. One __syncthreads per K-tile, NO inline asm: loads
//            get full MFMA cover, barrier drain is free. T1 XCD swizzle,
//            T2 both-sides XOR swizzle (validated pattern), gload_lds w=16.
//   Epilogue: out = (float)acc * scale_w[col] * Ra[row].

#define K_DIM 4096
#define N_DIM 12288

constexpr int BM = 256;
constexpr int BN = 256;
constexpr int BKB = 128;          // K-tile bytes (i8 elems)
constexpr int NT = K_DIM / BKB;   // 32

typedef float  f32x4  __attribute__((ext_vector_type(4)));
typedef int    i32x4  __attribute__((ext_vector_type(4)));
typedef short  bf16x8 __attribute__((ext_vector_type(8)));
typedef unsigned short u16x4 __attribute__((ext_vector_type(4)));

__device__ __forceinline__ unsigned short f32_to_bf16(float f) {
    unsigned int u = __builtin_bit_cast(unsigned int, f);
    u += 0x7FFFu + ((u >> 16) & 1u);
    return (unsigned short)(u >> 16);
}

// ---------------- Pass 1a: per-row quantize A -> int8 (linear) ----------------

__global__ __launch_bounds__(256)
void quant_a_kernel(const float* __restrict__ A,
                    signed char* __restrict__ Aq,
                    float* __restrict__ Ra) {
    const int row  = blockIdx.x;
    const int tid  = threadIdx.x;
    const int lane = tid & 63;
    const int wid  = tid >> 6;
    const float* arow = A + (size_t)row * K_DIM;
    const int base = tid * 16;

    f32x4 v[4];
    #pragma unroll
    for (int i = 0; i < 4; ++i)
        v[i] = *(const f32x4*)(arow + base + i * 4);

    float mx = 0.f;
    #pragma unroll
    for (int i = 0; i < 4; ++i)
        #pragma unroll
        for (int j = 0; j < 4; ++j)
            mx = fmaxf(mx, fabsf(v[i][j]));

    #pragma unroll
    for (int off = 32; off > 0; off >>= 1)
        mx = fmaxf(mx, __shfl_xor(mx, off));

    __shared__ float wmax[4];
    if (lane == 0) wmax[wid] = mx;
    __syncthreads();
    mx = fmaxf(fmaxf(wmax[0], wmax[1]), fmaxf(wmax[2], wmax[3]));

    const float inv = (mx > 0.f) ? (127.0f / mx) : 0.f;
    if (tid == 0) Ra[row] = mx * (1.0f / 127.0f);

    int p[4];
    #pragma unroll
    for (int i = 0; i < 4; ++i) {
        int b0 = (int)rintf(v[i][0] * inv);
        int b1 = (int)rintf(v[i][1] * inv);
        int b2 = (int)rintf(v[i][2] * inv);
        int b3 = (int)rintf(v[i][3] * inv);
        p[i] = (b0 & 255) | ((b1 & 255) << 8) | ((b2 & 255) << 16) | (b3 << 24);
    }
    *(i32x4*)(Aq + (size_t)row * K_DIM + base) = *(i32x4*)p;
}

// ---------------- Pass 1b: W int32 -> int8 linear (exact) ----------------

__global__ __launch_bounds__(256)
void cvt_w8_kernel(const int* __restrict__ W, signed char* __restrict__ Wq, int n16) {
    int stride = gridDim.x * blockDim.x;
    for (int i = blockIdx.x * blockDim.x + threadIdx.x; i < n16; i += stride) {
        const int* src = W + (size_t)i * 16;
        int p[4];
        #pragma unroll
        for (int q = 0; q < 4; ++q) {
            const i32x4 w = *(const i32x4*)(src + q * 4);
            p[q] = (w[0] & 255) | ((w[1] & 255) << 8) | ((w[2] & 255) << 16) | (w[3] << 24);
        }
        *(i32x4*)(Wq + (size_t)i * 16) = *(i32x4*)p;
    }
}

// ---------------- Pass 2: 256^2 big-wave-tile i8 GEMM ----------------

__device__ __forceinline__ void gload_lds16(const void* g, void* l) {
    __builtin_amdgcn_global_load_lds(
        (const __attribute__((address_space(1))) unsigned int*)g,
        (__attribute__((address_space(3))) unsigned int*)l,
        16, 0, 0);
}

__global__ __launch_bounds__(256)
void gemm_i8_big(const signed char* __restrict__ Aq,   // [M,K] i8
                 const signed char* __restrict__ Wq,   // [N,K] i8
                 const float* __restrict__ Sw,         // [N]
                 const float* __restrict__ Ra,         // [M]
                 float* __restrict__ Out,              // [M,N]
                 int M) {
    __shared__ __align__(16) unsigned char As8[2][BM * BKB];   // 2 x 32 KB
    __shared__ __align__(16) unsigned char Bs8[2][BN * BKB];   // 2 x 32 KB

    const int tid  = threadIdx.x;
    const int lane = tid & 63;
    const int wid  = tid >> 6;          // 0..3
    const int wm   = wid >> 1;          // 0..1  (128-row half)
    const int wn   = wid & 1;           // 0..1  (128-col half)

    // T1: XCD swizzle (768 blocks, 96/XCD), column-major within chunk
    const int nwgy = M / BM;                 // 16
    const int nwg  = (N_DIM / BN) * nwgy;    // 768
    const int cpx  = nwg >> 3;               // 96
    const int bid  = blockIdx.x;
    const int swz  = (bid & 7) * cpx + (bid >> 3);
    const int bx   = swz / nwgy;
    const int by   = swz % nwgy;
    const int bm   = by * BM;
    const int bn   = bx * BN;

    // staging: 4 waves, 8 issues per 32KB tile. chunk c = i*4+wid,
    // lane writes c*1024B + lane*16B -> row c*8+(lane>>3), colB (lane&7)*16.
    // T2 rule #21: pre-swizzle GLOBAL col by row&7 (= lane>>3); LDS linear.
    const int scolB = ((lane & 7) ^ (lane >> 3)) * 16;      // bytes

    #define STG_T(G, gbase, k0B, L)                                                 \
        _Pragma("unroll") for (int i_ = 0; i_ < 8; ++i_)                            \
            gload_lds16((G) + (size_t)((gbase) + i_ * 32 + wid * 8 + (lane >> 3)) * K_DIM \
                            + (k0B) + scolB,                                        \
                        (L) + (i_ * 4 + wid) * 1024);

    i32x4 acc[8][8];
    #pragma unroll
    for (int i = 0; i < 8; ++i)
        #pragma unroll
        for (int j = 0; j < 8; ++j)
            acc[i][j] = (i32x4){0, 0, 0, 0};

    const int c0   = lane & 15;
    const int kgB  = (lane >> 4) * 16;     // byte offset of lane's K-group
    const int rswB = (c0 & 7) * 16;        // read-side swizzle (row&7 == c0&7)

    const int aoffA = (wm * 128 + c0) * BKB;
    const int aoffB = (wn * 128 + c0) * BKB;

    // ---- prologue: stage tile0 into buf0 ----
    STG_T(Aq, bm, 0, &As8[0][0]);
    STG_T(Wq, bn, 0, &Bs8[0][0]);
    __syncthreads();    // drains vmcnt -> tile0 ready

    // ---- K-loop: one barrier per K-tile, no inline asm.
    //   { read 32 frags(cur) ; stage tile t+1 -> other buf ; 128 MFMA ;
    //     __syncthreads (drains lgkm + vmcnt, both covered by MFMA) }
    for (int t = 0; t < NT; ++t) {
        const int cur = t & 1;
        const unsigned char* Ac = &As8[cur][0];
        const unsigned char* Bc = &Bs8[cur][0];
        unsigned char* An = &As8[cur ^ 1][0];
        unsigned char* Bn = &Bs8[cur ^ 1][0];

        i32x4 af[8][2];
        i32x4 bf[8][2];
        #pragma unroll
        for (int mf = 0; mf < 8; ++mf)
            #pragma unroll
            for (int ks = 0; ks < 2; ++ks)
                af[mf][ks] = *(const i32x4*)&Ac[aoffA + mf * 16 * BKB + ((ks * 64 + kgB) ^ rswB)];
        #pragma unroll
        for (int nf = 0; nf < 8; ++nf)
            #pragma unroll
            for (int ks = 0; ks < 2; ++ks)
                bf[nf][ks] = *(const i32x4*)&Bc[aoffB + nf * 16 * BKB + ((ks * 64 + kgB) ^ rswB)];

        if (t + 1 < NT) {
            const int k1 = (t + 1) * BKB;
            STG_T(Aq, bm, k1, An);
            STG_T(Wq, bn, k1, Bn);
        }

        #pragma unroll
        for (int ks = 0; ks < 2; ++ks)
            #pragma unroll
            for (int mf = 0; mf < 8; ++mf)
                #pragma unroll
                for (int nf = 0; nf < 8; ++nf)
                    acc[mf][nf] = __builtin_amdgcn_mfma_i32_16x16x64_i8(
                        af[mf][ks], bf[nf][ks], acc[mf][nf], 0, 0, 0);

        __syncthreads();
    }
    #undef STG_T

    // ---- epilogue: C/D col = lane&15 (B idx), row = (lane>>4)*4 + j (A idx) ----
    const int r0 = (lane >> 4) * 4;
    float rav[8][4];
    #pragma unroll
    for (int mf = 0; mf < 8; ++mf)
        #pragma unroll
        for (int j = 0; j < 4; ++j)
            rav[mf][j] = Ra[bm + wm * 128 + mf * 16 + r0 + j];

    #pragma unroll
    for (int nf = 0; nf < 8; ++nf) {
        const int col = bn + wn * 128 + nf * 16 + c0;
        const float s = Sw[col];
        #pragma unroll
        for (int mf = 0; mf < 8; ++mf) {
            const int rowb = bm + wm * 128 + mf * 16 + r0;
            #pragma unroll
            for (int j = 0; j < 4; ++j)
                Out[(size_t)(rowb + j) * N_DIM + col] = (float)acc[mf][nf][j] * s * rav[mf][j];
        }
    }
}

// ---------------- Fallback (fused bf16, if ws too small) ----------------

constexpr int FBM = 128, FBN = 128, FBK = 64, FPAD = 8;

__global__ __launch_bounds__(256)
void qlinear_fused_kernel(const float* __restrict__ A, const int* __restrict__ Wqi,
                          const float* __restrict__ Sw, float* __restrict__ Out, int M) {
    __shared__ unsigned short Asf[FBM][FBK + FPAD];
    __shared__ unsigned short Bsf[FBN][FBK + FPAD];
    const int tid  = threadIdx.x;
    const int lane = tid & 63;
    const int wid  = tid >> 6;
    const int wm   = wid >> 1;
    const int wn   = wid & 1;
    const int bm = blockIdx.y * FBM;
    const int bn = blockIdx.x * FBN;
    const int rowT = tid >> 4;
    const int kq   = tid & 15;
    f32x4 acc[4][4];
    #pragma unroll
    for (int i = 0; i < 4; ++i)
        #pragma unroll
        for (int j = 0; j < 4; ++j) acc[i][j] = (f32x4){0.f,0.f,0.f,0.f};
    const int c0 = lane & 15;
    const int kg = (lane >> 4) * 8;
    for (int k0 = 0; k0 < K_DIM; k0 += FBK) {
        #pragma unroll
        for (int it = 0; it < 8; ++it) {
            const int r = it * 16 + rowT;
            const f32x4 a4 = *(const f32x4*)(A + (size_t)(bm + r) * K_DIM + k0 + kq * 4);
            u16x4 h;
            h[0]=f32_to_bf16(a4[0]); h[1]=f32_to_bf16(a4[1]);
            h[2]=f32_to_bf16(a4[2]); h[3]=f32_to_bf16(a4[3]);
            *(u16x4*)&Asf[r][kq*4] = h;
        }
        #pragma unroll
        for (int it = 0; it < 8; ++it) {
            const int r = it * 16 + rowT;
            const i32x4 w4 = *(const i32x4*)(Wqi + (size_t)(bn + r) * K_DIM + k0 + kq * 4);
            u16x4 h;
            h[0]=f32_to_bf16((float)w4[0]); h[1]=f32_to_bf16((float)w4[1]);
            h[2]=f32_to_bf16((float)w4[2]); h[3]=f32_to_bf16((float)w4[3]);
            *(u16x4*)&Bsf[r][kq*4] = h;
        }
        __syncthreads();
        #pragma unroll
        for (int ks = 0; ks < 2; ++ks) {
            const int kk = ks * 32 + kg;
            bf16x8 af2[4], bfr[4];
            #pragma unroll
            for (int mf = 0; mf < 4; ++mf)
                af2[mf] = *(const bf16x8*)&Asf[wm*64 + mf*16 + c0][kk];
            #pragma unroll
            for (int nf = 0; nf < 4; ++nf)
                bfr[nf] = *(const bf16x8*)&Bsf[wn*64 + nf*16 + c0][kk];
            #pragma unroll
            for (int mf = 0; mf < 4; ++mf)
                #pragma unroll
                for (int nf = 0; nf < 4; ++nf)
                    acc[mf][nf] = __builtin_amdgcn_mfma_f32_16x16x32_bf16(
                        af2[mf], bfr[nf], acc[mf][nf], 0, 0, 0);
        }
        __syncthreads();
    }
    const int r0 = (lane >> 4) * 4;
    #pragma unroll
    for (int nf = 0; nf < 4; ++nf) {
        const int col = bn + wn*64 + nf*16 + c0;
        const float s = Sw[col];
        #pragma unroll
        for (int mf = 0; mf < 4; ++mf) {
            const int rowb = bm + wm*64 + mf*16 + r0;
            #pragma unroll
            for (int j = 0; j < 4; ++j)
                Out[(size_t)(rowb + j) * N_DIM + col] = acc[mf][nf][j] * s;
        }
    }
}

extern "C" void kernel_launch(void* const* d_in, const int* in_sizes, int n_in,
                              void* d_out, int out_size, void* d_ws, size_t ws_size,
                              hipStream_t stream) {
    const float* inp = (const float*)d_in[0];
    const int*   qw  = (const int*)d_in[1];
    const float* sw  = (const float*)d_in[2];
    float*       out = (float*)d_out;

    const int M = in_sizes[0] / K_DIM;                         // 4096
    const size_t nA = (size_t)M * K_DIM;                       // A elements
    const size_t nW = (size_t)N_DIM * K_DIM;                   // W elements
    const size_t needQ = nA + nW + (size_t)M * sizeof(float);  // ~67 MiB

    if (ws_size >= needQ && (M % BM) == 0) {
        signed char* Aq  = (signed char*)d_ws;
        signed char* Wq8 = Aq + nA;
        float*       Ra  = (float*)(Wq8 + nW);
        quant_a_kernel<<<M, 256, 0, stream>>>(inp, Aq, Ra);
        cvt_w8_kernel<<<2048, 256, 0, stream>>>(qw, Wq8, (int)(nW / 16));
        dim3 grid((N_DIM / BN) * (M / BM));                    // 768
        gemm_i8_big<<<grid, 256, 0, stream>>>(Aq, Wq8, sw, Ra, out, M);
    } else {
        dim3 grid(N_DIM / FBN, M / FBM);
        qlinear_fused_kernel<<<grid, 256, 0, stream>>>(inp, qw, sw, out, M);
    }
}

// Round 16
// 313.219 us; speedup vs baseline: 1.5511x; 1.5511x over previous
//
#include <hip/hip_runtime.h>
#include <hip/hip_bf16.h>

// QuantizedLinear: out[M,N] = inp[M,K] @ (qw[N,K] * scale[N])^T
// M = 4096, K = 4096, N = 12288.
// Round 16: TWO-BLOCKS-PER-CU i8 GEMM (cross-block overlap, m114).
//   Pass 1a: per-row absmax-quantize A fp32 -> int8 linear [M][K] (+ Ra[m]).
//   Pass 1b: W int32 -> int8 linear [N][K] (exact).
//   Pass 2:  256x128 block, 4 waves (2x2) of 128x64, BK=64 -> LDS 48KB,
//            ~200 regs -> 2 blocks/CU (__launch_bounds__(256,2)).
//            Chunked LDS layout (16 rows x 64B per 1KB chunk) with slot
//            permutation idx=((s^(r&3))<<4)|r: frag reads exactly 2-way
//            (free), staging source pre-permuted (rule #21), gload_lds w=16.
//            One __syncthreads per K-tile; overlap comes from the other block.
//   Epilogue: out = (float)acc * scale_w[col] * Ra[row].

#define K_DIM 4096
#define N_DIM 12288

constexpr int BM = 256;
constexpr int BN = 128;
constexpr int BKB = 64;           // K-tile bytes (i8 elems)
constexpr int NT = K_DIM / BKB;   // 64

typedef float  f32x4  __attribute__((ext_vector_type(4)));
typedef int    i32x4  __attribute__((ext_vector_type(4)));
typedef short  bf16x8 __attribute__((ext_vector_type(8)));
typedef unsigned short u16x4 __attribute__((ext_vector_type(4)));

__device__ __forceinline__ unsigned short f32_to_bf16(float f) {
    unsigned int u = __builtin_bit_cast(unsigned int, f);
    u += 0x7FFFu + ((u >> 16) & 1u);
    return (unsigned short)(u >> 16);
}

// ---------------- Pass 1a: per-row quantize A -> int8 (linear) ----------------

__global__ __launch_bounds__(256)
void quant_a_kernel(const float* __restrict__ A,
                    signed char* __restrict__ Aq,
                    float* __restrict__ Ra) {
    const int row  = blockIdx.x;
    const int tid  = threadIdx.x;
    const int lane = tid & 63;
    const int wid  = tid >> 6;
    const float* arow = A + (size_t)row * K_DIM;
    const int base = tid * 16;

    f32x4 v[4];
    #pragma unroll
    for (int i = 0; i < 4; ++i)
        v[i] = *(const f32x4*)(arow + base + i * 4);

    float mx = 0.f;
    #pragma unroll
    for (int i = 0; i < 4; ++i)
        #pragma unroll
        for (int j = 0; j < 4; ++j)
            mx = fmaxf(mx, fabsf(v[i][j]));

    #pragma unroll
    for (int off = 32; off > 0; off >>= 1)
        mx = fmaxf(mx, __shfl_xor(mx, off));

    __shared__ float wmax[4];
    if (lane == 0) wmax[wid] = mx;
    __syncthreads();
    mx = fmaxf(fmaxf(wmax[0], wmax[1]), fmaxf(wmax[2], wmax[3]));

    const float inv = (mx > 0.f) ? (127.0f / mx) : 0.f;
    if (tid == 0) Ra[row] = mx * (1.0f / 127.0f);

    int p[4];
    #pragma unroll
    for (int i = 0; i < 4; ++i) {
        int b0 = (int)rintf(v[i][0] * inv);
        int b1 = (int)rintf(v[i][1] * inv);
        int b2 = (int)rintf(v[i][2] * inv);
        int b3 = (int)rintf(v[i][3] * inv);
        p[i] = (b0 & 255) | ((b1 & 255) << 8) | ((b2 & 255) << 16) | (b3 << 24);
    }
    *(i32x4*)(Aq + (size_t)row * K_DIM + base) = *(i32x4*)p;
}

// ---------------- Pass 1b: W int32 -> int8 linear (exact) ----------------

__global__ __launch_bounds__(256)
void cvt_w8_kernel(const int* __restrict__ W, signed char* __restrict__ Wq, int n16) {
    int stride = gridDim.x * blockDim.x;
    for (int i = blockIdx.x * blockDim.x + threadIdx.x; i < n16; i += stride) {
        const int* src = W + (size_t)i * 16;
        int p[4];
        #pragma unroll
        for (int q = 0; q < 4; ++q) {
            const i32x4 w = *(const i32x4*)(src + q * 4);
            p[q] = (w[0] & 255) | ((w[1] & 255) << 8) | ((w[2] & 255) << 16) | (w[3] << 24);
        }
        *(i32x4*)(Wq + (size_t)i * 16) = *(i32x4*)p;
    }
}

// ---------------- Pass 2: 256x128 i8 GEMM, 2 blocks/CU ----------------
// LDS chunk = 1KB = 16 rows x 64B. Slot index for (row r, 16B-slot s):
//   idx = ((s ^ (r&3)) << 4) | r      (bijective on 6 bits)
// Frag read (lane l wants row l&15, slot l>>4):
//   byte = (((l>>4) ^ (l&3)) << 8) + (l&15)*16
//   -> quad index = l % 8 -> each of 8 bank-quads hit exactly 2x (free).
// Staging (lane l writes LDS l*16 = idx l): source row = l&15,
//   slot = (l>>4) ^ (l&3) -> same involution on both sides.

__device__ __forceinline__ void gload_lds16(const void* g, void* l) {
    __builtin_amdgcn_global_load_lds(
        (const __attribute__((address_space(1))) unsigned int*)g,
        (__attribute__((address_space(3))) unsigned int*)l,
        16, 0, 0);
}

__global__ __launch_bounds__(256, 2)
void gemm_i8_2b(const signed char* __restrict__ Aq,   // [M,K] i8
                const signed char* __restrict__ Wq,   // [N,K] i8
                const float* __restrict__ Sw,         // [N]
                const float* __restrict__ Ra,         // [M]
                float* __restrict__ Out,              // [M,N]
                int M) {
    __shared__ __align__(16) unsigned char As8[2][BM * BKB];   // 2 x 16 KB
    __shared__ __align__(16) unsigned char Bs8[2][BN * BKB];   // 2 x 8 KB

    const int tid  = threadIdx.x;
    const int lane = tid & 63;
    const int wid  = tid >> 6;          // 0..3
    const int wm   = wid >> 1;          // 0..1  (128-row half)
    const int wn   = wid & 1;           // 0..1  (64-col half)

    // T1: XCD swizzle (1536 blocks, 192/XCD), column-major within chunk
    // (16 consecutive blocks share one 512KB W-panel -> L2).
    const int nwgy = M / BM;                 // 16
    const int nwg  = (N_DIM / BN) * nwgy;    // 1536
    const int cpx  = nwg >> 3;               // 192
    const int bid  = blockIdx.x;
    const int swz  = (bid & 7) * cpx + (bid >> 3);
    const int bx   = swz / nwgy;
    const int by   = swz % nwgy;
    const int bm   = by * BM;
    const int bn   = bx * BN;

    // staging source (per lane): row-in-group, permuted 16B slot
    const int sr   = lane & 15;
    const int sc16 = (((lane >> 4) ^ (lane & 3)) * 16);   // bytes in 64B row

    // A: 16 chunks (256 rows), 4 issues x 4 waves; B: 8 chunks, 2 issues.
    #define STG_A(k0B, L)                                                            \
        _Pragma("unroll") for (int i_ = 0; i_ < 4; ++i_)                            \
            gload_lds16(Aq + (size_t)(bm + (i_ * 4 + wid) * 16 + sr) * K_DIM        \
                            + (k0B) + sc16,                                         \
                        (L) + (i_ * 4 + wid) * 1024);
    #define STG_B(k0B, L)                                                            \
        _Pragma("unroll") for (int i_ = 0; i_ < 2; ++i_)                            \
            gload_lds16(Wq + (size_t)(bn + (i_ * 4 + wid) * 16 + sr) * K_DIM        \
                            + (k0B) + sc16,                                         \
                        (L) + (i_ * 4 + wid) * 1024);

    i32x4 acc[8][4];
    #pragma unroll
    for (int i = 0; i < 8; ++i)
        #pragma unroll
        for (int j = 0; j < 4; ++j)
            acc[i][j] = (i32x4){0, 0, 0, 0};

    // fragment read offset within a 1KB chunk (see header comment)
    const int fro = ((((lane >> 4) ^ (lane & 3)) << 8) | ((lane & 15) << 4));

    // ---- prologue ----
    STG_A(0, &As8[0][0]);
    STG_B(0, &Bs8[0][0]);
    __syncthreads();

    for (int t = 0; t < NT; ++t) {
        const int cur = t & 1;

        i32x4 af[8];
        i32x4 bf[4];
        #pragma unroll
        for (int mf = 0; mf < 8; ++mf)
            af[mf] = *(const i32x4*)&As8[cur][(wm * 8 + mf) * 1024 + fro];
        #pragma unroll
        for (int nf = 0; nf < 4; ++nf)
            bf[nf] = *(const i32x4*)&Bs8[cur][(wn * 4 + nf) * 1024 + fro];

        if (t + 1 < NT) {
            const int k1 = (t + 1) * BKB;
            STG_A(k1, &As8[cur ^ 1][0]);
            STG_B(k1, &Bs8[cur ^ 1][0]);
        }

        __builtin_amdgcn_s_setprio(1);
        #pragma unroll
        for (int mf = 0; mf < 8; ++mf)
            #pragma unroll
            for (int nf = 0; nf < 4; ++nf)
                acc[mf][nf] = __builtin_amdgcn_mfma_i32_16x16x64_i8(
                    af[mf], bf[nf], acc[mf][nf], 0, 0, 0);
        __builtin_amdgcn_s_setprio(0);

        __syncthreads();
    }
    #undef STG_A
    #undef STG_B

    // ---- epilogue: C/D col = lane&15 (B idx), row = (lane>>4)*4 + j (A idx) ----
    const int c0 = lane & 15;
    const int r0 = (lane >> 4) * 4;
    float rav[8][4];
    #pragma unroll
    for (int mf = 0; mf < 8; ++mf)
        #pragma unroll
        for (int j = 0; j < 4; ++j)
            rav[mf][j] = Ra[bm + wm * 128 + mf * 16 + r0 + j];

    #pragma unroll
    for (int nf = 0; nf < 4; ++nf) {
        const int col = bn + wn * 64 + nf * 16 + c0;
        const float s = Sw[col];
        #pragma unroll
        for (int mf = 0; mf < 8; ++mf) {
            const int rowb = bm + wm * 128 + mf * 16 + r0;
            #pragma unroll
            for (int j = 0; j < 4; ++j)
                Out[(size_t)(rowb + j) * N_DIM + col] = (float)acc[mf][nf][j] * s * rav[mf][j];
        }
    }
}

// ---------------- Fallback (fused bf16, if ws too small) ----------------

constexpr int FBM = 128, FBN = 128, FBK = 64, FPAD = 8;

__global__ __launch_bounds__(256)
void qlinear_fused_kernel(const float* __restrict__ A, const int* __restrict__ Wqi,
                          const float* __restrict__ Sw, float* __restrict__ Out, int M) {
    __shared__ unsigned short Asf[FBM][FBK + FPAD];
    __shared__ unsigned short Bsf[FBN][FBK + FPAD];
    const int tid  = threadIdx.x;
    const int lane = tid & 63;
    const int wid  = tid >> 6;
    const int wm   = wid >> 1;
    const int wn   = wid & 1;
    const int bm = blockIdx.y * FBM;
    const int bn = blockIdx.x * FBN;
    const int rowT = tid >> 4;
    const int kq   = tid & 15;
    f32x4 acc[4][4];
    #pragma unroll
    for (int i = 0; i < 4; ++i)
        #pragma unroll
        for (int j = 0; j < 4; ++j) acc[i][j] = (f32x4){0.f,0.f,0.f,0.f};
    const int c0 = lane & 15;
    const int kg = (lane >> 4) * 8;
    for (int k0 = 0; k0 < K_DIM; k0 += FBK) {
        #pragma unroll
        for (int it = 0; it < 8; ++it) {
            const int r = it * 16 + rowT;
            const f32x4 a4 = *(const f32x4*)(A + (size_t)(bm + r) * K_DIM + k0 + kq * 4);
            u16x4 h;
            h[0]=f32_to_bf16(a4[0]); h[1]=f32_to_bf16(a4[1]);
            h[2]=f32_to_bf16(a4[2]); h[3]=f32_to_bf16(a4[3]);
            *(u16x4*)&Asf[r][kq*4] = h;
        }
        #pragma unroll
        for (int it = 0; it < 8; ++it) {
            const int r = it * 16 + rowT;
            const i32x4 w4 = *(const i32x4*)(Wqi + (size_t)(bn + r) * K_DIM + k0 + kq * 4);
            u16x4 h;
            h[0]=f32_to_bf16((float)w4[0]); h[1]=f32_to_bf16((float)w4[1]);
            h[2]=f32_to_bf16((float)w4[2]); h[3]=f32_to_bf16((float)w4[3]);
            *(u16x4*)&Bsf[r][kq*4] = h;
        }
        __syncthreads();
        #pragma unroll
        for (int ks = 0; ks < 2; ++ks) {
            const int kk = ks * 32 + kg;
            bf16x8 af2[4], bfr[4];
            #pragma unroll
            for (int mf = 0; mf < 4; ++mf)
                af2[mf] = *(const bf16x8*)&Asf[wm*64 + mf*16 + c0][kk];
            #pragma unroll
            for (int nf = 0; nf < 4; ++nf)
                bfr[nf] = *(const bf16x8*)&Bsf[wn*64 + nf*16 + c0][kk];
            #pragma unroll
            for (int mf = 0; mf < 4; ++mf)
                #pragma unroll
                for (int nf = 0; nf < 4; ++nf)
                    acc[mf][nf] = __builtin_amdgcn_mfma_f32_16x16x32_bf16(
                        af2[mf], bfr[nf], acc[mf][nf], 0, 0, 0);
        }
        __syncthreads();
    }
    const int r0 = (lane >> 4) * 4;
    #pragma unroll
    for (int nf = 0; nf < 4; ++nf) {
        const int col = bn + wn*64 + nf*16 + c0;
        const float s = Sw[col];
        #pragma unroll
        for (int mf = 0; mf < 4; ++mf) {
            const int rowb = bm + wm*64 + mf*16 + r0;
            #pragma unroll
            for (int j = 0; j < 4; ++j)
                Out[(size_t)(rowb + j) * N_DIM + col] = acc[mf][nf][j] * s;
        }
    }
}

extern "C" void kernel_launch(void* const* d_in, const int* in_sizes, int n_in,
                              void* d_out, int out_size, void* d_ws, size_t ws_size,
                              hipStream_t stream) {
    const float* inp = (const float*)d_in[0];
    const int*   qw  = (const int*)d_in[1];
    const float* sw  = (const float*)d_in[2];
    float*       out = (float*)d_out;

    const int M = in_sizes[0] / K_DIM;                         // 4096
    const size_t nA = (size_t)M * K_DIM;                       // A elements
    const size_t nW = (size_t)N_DIM * K_DIM;                   // W elements
    const size_t needQ = nA + nW + (size_t)M * sizeof(float);  // ~67 MiB

    if (ws_size >= needQ && (M % BM) == 0) {
        signed char* Aq  = (signed char*)d_ws;
        signed char* Wq8 = Aq + nA;
        float*       Ra  = (float*)(Wq8 + nW);
        quant_a_kernel<<<M, 256, 0, stream>>>(inp, Aq, Ra);
        cvt_w8_kernel<<<2048, 256, 0, stream>>>(qw, Wq8, (int)(nW / 16));
        dim3 grid((N_DIM / BN) * (M / BM));                    // 1536
        gemm_i8_2b<<<grid, 256, 0, stream>>>(Aq, Wq8, sw, Ra, out, M);
    } else {
        dim3 grid(N_DIM / FBN, M / FBM);
        qlinear_fused_kernel<<<grid, 256, 0, stream>>>(inp, qw, sw, out, M);
    }
}